// Round 3
// baseline (397.403 us; speedup 1.0000x reference)
//
#include <hip/hip_runtime.h>

#define F 1024
#define S 128
#define H 16
#define D 64
#define CK 64        // K per tile (BK)
#define NCHUNK 16    // 1024 / 64

typedef short bf16x8 __attribute__((ext_vector_type(8)));
typedef float f32x4  __attribute__((ext_vector_type(4)));

// ws: xs2[128 bg][16 ch][2048 units] (B-tiles: rows = 2 batches' s, k-major)
//     wb2[ 8 hg][16 ch][2048 units] (A-tiles: rows = 2 heads' [Wq;Wk], k-major)
// unit(kc,row) = kc*256 + row ; kc in [0,8) (8 bf16 of k each), row in [0,256)
#define XS_UNITS ((size_t)128 * NCHUNK * 2048)
#define WB_UNITS ((size_t)8 * NCHUNK * 2048)
#define WS_NEED ((XS_UNITS + WB_UNITS) * 16)

#define MAIN_LDS_BYTES (8192 * 16 + 8 * 128 * 4 + 128 * 4)

__device__ __forceinline__ unsigned short f2bf(float f) {
    unsigned u = __float_as_uint(f);
    u += 0x7fffu + ((u >> 16) & 1u);   // round-to-nearest-even
    return (unsigned short)(u >> 16);
}

__device__ __forceinline__ uint4 pack8(const float* f) {
    uint4 u;
    u.x = (unsigned)f2bf(f[0]) | ((unsigned)f2bf(f[1]) << 16);
    u.y = (unsigned)f2bf(f[2]) | ((unsigned)f2bf(f[3]) << 16);
    u.z = (unsigned)f2bf(f[4]) | ((unsigned)f2bf(f[5]) << 16);
    u.w = (unsigned)f2bf(f[6]) | ((unsigned)f2bf(f[7]) << 16);
    return u;
}

typedef __attribute__((address_space(1))) const unsigned int as1_u32;
typedef __attribute__((address_space(3))) unsigned int as3_u32;

__device__ __forceinline__ void async_cp16(const uint4* g, uint4* l) {
    __builtin_amdgcn_global_load_lds((as1_u32*)g, (as3_u32*)l, 16, 0, 0);
}

__device__ __forceinline__ void bar()   { __builtin_amdgcn_s_barrier(); }
__device__ __forceinline__ void sb0()   { __builtin_amdgcn_sched_barrier(0); }
__device__ __forceinline__ void lgkm0() { asm volatile("s_waitcnt lgkmcnt(0)"); }

template<int N> __device__ __forceinline__ void vmw() {
    asm volatile("s_waitcnt vmcnt(%0)" :: "n"(N));
}

// ---------------- prep: fp32 -> bf16, k-major tiles; 4 chunks per block (A/B vs round-2) ----------------
__global__ void prep(const float* __restrict__ x,
                     const float* __restrict__ Wq,
                     const float* __restrict__ Wk,
                     uint4* __restrict__ xs,
                     uint4* __restrict__ wb)
{
    __shared__ float4 t4[64 * 33];      // row stride 33 float4 = 132 floats
    const int tid = threadIdx.x;
    const int blk = blockIdx.x;
    if (blk < 1024) {
        // x tiles: batch b = blk>>2, chunks (blk&3)*4 + cc
        const int b = blk >> 2;
#pragma unroll 1
        for (int cc = 0; cc < 4; ++cc) {
            const int ch = (blk & 3) * 4 + cc;
            const float4* src = (const float4*)(x + ((size_t)b * F + ch * CK) * S);
            float4 v[8];
#pragma unroll
            for (int j = 0; j < 8; ++j) v[j] = src[tid + j * 256];
            __syncthreads();   // protect t4 from previous iteration's readers
#pragma unroll
            for (int j = 0; j < 8; ++j) {
                const int e4 = tid + j * 256;
                t4[(e4 >> 5) * 33 + (e4 & 31)] = v[j];
            }
            __syncthreads();
            const float* tile = (const float*)t4;
            uint4* dst = xs + ((size_t)(b >> 1) * NCHUNK + ch) * 2048 + (b & 1) * 128;
#pragma unroll
            for (int j = 0; j < 4; ++j) {
                const int u  = tid + j * 256;
                const int kc = u >> 7;
                const int s  = u & 127;
                float f[8];
#pragma unroll
                for (int jj = 0; jj < 8; ++jj) f[jj] = tile[(kc * 8 + jj) * 132 + s];
                dst[kc * 256 + s] = pack8(f);
            }
        }
    } else {
        // W tiles: head h = (blk-1024)>>2, chunks ((blk-1024)&3)*4 + cc
        const int blk2 = blk - 1024;
        const int h = blk2 >> 2;
#pragma unroll 1
        for (int cc = 0; cc < 4; ++cc) {
            const int ch = (blk2 & 3) * 4 + cc;
            uint4* dst = wb + ((size_t)(h >> 1) * NCHUNK + ch) * 2048 + (h & 1) * 128;
#pragma unroll
            for (int j = 0; j < 4; ++j) {
                const int u  = tid + j * 256;
                const int kc = u >> 7;
                const int m  = u & 127;
                const float* srcp = (m < 64)
                    ? (Wq + (size_t)(h * D + m) * F + ch * CK + kc * 8)
                    : (Wk + (size_t)(h * D + m - 64) * F + ch * CK + kc * 8);
                float f[8];
                float4 a = ((const float4*)srcp)[0];
                float4 c = ((const float4*)srcp)[1];
                f[0] = a.x; f[1] = a.y; f[2] = a.z; f[3] = a.w;
                f[4] = c.x; f[5] = c.y; f[6] = c.z; f[7] = c.w;
                dst[kc * 256 + m] = pack8(f);
            }
        }
    }
}

// ---------------- main kernel helpers ----------------
__device__ __forceinline__ void read4(const uint4* mat, int base, bf16x8 (&r)[4]) {
    r[0] = *(const bf16x8*)&mat[base];
    r[1] = *(const bf16x8*)&mat[base + 16];
    r[2] = *(const bf16x8*)&mat[base + 32];
    r[3] = *(const bf16x8*)&mat[base + 48];
}

template<int RB>
__device__ __forceinline__ void mfma16(f32x4 (&acc)[8][4], const bf16x8 (&af)[4], const bf16x8 (&br)[4]) {
#pragma unroll
    for (int mt = 0; mt < 4; ++mt)
#pragma unroll
        for (int nt = 0; nt < 4; ++nt)
            acc[RB + mt][nt] = __builtin_amdgcn_mfma_f32_16x16x32_bf16(af[mt], br[nt], acc[RB + mt][nt], 0, 0, 0);
}

// half-tiles (16 KB each): 0 = A.ks0, 1 = B.ks0, 2 = A.ks1, 3 = B.ks1
template<int HALF>
__device__ __forceinline__ void stage_half(uint4* mat, const uint4* wbase, const uint4* xbase,
                                           int tgt, int wv, int lane) {
    const int bufb = (tgt & 1) * 4096;
    const uint4* g;
    int l;
    if constexpr (HALF == 0)      { g = wbase + (size_t)tgt * 2048;        l = bufb;        }
    else if constexpr (HALF == 1) { g = xbase + (size_t)tgt * 2048;        l = bufb + 2048; }
    else if constexpr (HALF == 2) { g = wbase + (size_t)tgt * 2048 + 1024; l = bufb + 1024; }
    else                          { g = xbase + (size_t)tgt * 2048 + 1024; l = bufb + 3072; }
    async_cp16(g + wv * 128 + lane,      &mat[l + wv * 128]);
    async_cp16(g + wv * 128 + 64 + lane, &mat[l + wv * 128 + 64]);
}

// One K-tile (BK=64): 4 phases {ds_read | 1 half-tile DMA | barrier | MFMA}.
// Counted vmcnt ledger: W1 (after ph2) completes ks1(t); W2 (after ph4) completes ks0(t+1).
template<int CUR, bool I1, bool I2, int W1, int W2, bool DW2>
__device__ __forceinline__ void ktile(uint4* mat, const uint4* wbase, const uint4* xbase,
                                      int t, int wv, int lane, int wm, int wn, int q, int l15,
                                      f32x4 (&acc)[8][4])
{
    bf16x8 af[4], br[4];
    const int abase = CUR * 4096 + wm * 128 + l15;
    const int bbase = CUR * 4096 + 2048 + wn * 64 + l15;
    const int kq = q * 256;
    // ph1: ks0, row-half 0
    read4(mat, abase + kq, af);
    read4(mat, bbase + kq, br);
    if constexpr (I1) stage_half<2>(mat, wbase, xbase, t + 1, wv, lane);
    bar(); lgkm0(); sb0();
    __builtin_amdgcn_s_setprio(1); mfma16<0>(acc, af, br); __builtin_amdgcn_s_setprio(0);
    bar(); sb0();
    // ph2: ks0, row-half 1 (br reused from regs)
    read4(mat, abase + kq + 64, af);
    if constexpr (I1) stage_half<3>(mat, wbase, xbase, t + 1, wv, lane);
    bar(); lgkm0(); sb0();
    __builtin_amdgcn_s_setprio(1); mfma16<4>(acc, af, br); __builtin_amdgcn_s_setprio(0);
    vmw<W1>(); bar(); sb0();
    // ph3: ks1, row-half 0
    read4(mat, abase + kq + 1024, af);
    read4(mat, bbase + kq + 1024, br);
    if constexpr (I2) stage_half<0>(mat, wbase, xbase, t + 2, wv, lane);
    bar(); lgkm0(); sb0();
    __builtin_amdgcn_s_setprio(1); mfma16<0>(acc, af, br); __builtin_amdgcn_s_setprio(0);
    bar(); sb0();
    // ph4: ks1, row-half 1
    read4(mat, abase + kq + 1024 + 64, af);
    if constexpr (I2) stage_half<1>(mat, wbase, xbase, t + 2, wv, lane);
    bar(); lgkm0(); sb0();
    __builtin_amdgcn_s_setprio(1); mfma16<4>(acc, af, br); __builtin_amdgcn_s_setprio(0);
    if constexpr (DW2) { vmw<W2>(); bar(); sb0(); }
}

// ---------------- main: 256x256x1024 GEMM (2 heads x 2 batches) + pair-parallel attention epilogue ----------------
__launch_bounds__(512, 2)
__global__ void attn_main(const float* __restrict__ x,
                          const uint4* __restrict__ xs,
                          const uint4* __restrict__ wb,
                          const float* __restrict__ bq,
                          const float* __restrict__ bk,
                          const float* __restrict__ Wo,
                          const float* __restrict__ bo,
                          float* __restrict__ out)
{
    extern __shared__ char smraw[];
    uint4* mat   = (uint4*)smraw;                       // 8192 units = 2 x (A 2048 + B 2048)
    float* wpart = (float*)(smraw + 8192 * 16);         // [8][128]

    const int tid  = threadIdx.x;
    const int lane = tid & 63;
    const int wv   = tid >> 6;
    const int l15  = lane & 15;
    const int q    = lane >> 4;
    const int wm   = wv >> 2;      // 2 waves rows
    const int wn   = wv & 3;       // 4 waves cols

    // XCD-aware swizzle: 1024 blocks, 8 XCDs; per XCD 16 bg x 8 hg
    const int g    = blockIdx.x;
    const int xcd  = g & 7;
    const int slot = g >> 3;
    const int bg   = xcd * 16 + (slot & 15);   // batch-pair [0,128)
    const int hg   = slot >> 4;                // head-pair  [0,8)

    const uint4* wbase = wb + (size_t)hg * NCHUNK * 2048;
    const uint4* xbase = xs + (size_t)bg * NCHUNK * 2048;

    f32x4 acc[8][4];
#pragma unroll
    for (int mi = 0; mi < 8; ++mi)
#pragma unroll
        for (int ni = 0; ni < 4; ++ni) acc[mi][ni] = (f32x4){0.f, 0.f, 0.f, 0.f};

    // prologue: tile0 all 4 halves + tile1 ks0 halves; wait oldest 4 loads (tile0.ks0)
    stage_half<0>(mat, wbase, xbase, 0, wv, lane);
    stage_half<1>(mat, wbase, xbase, 0, wv, lane);
    stage_half<2>(mat, wbase, xbase, 0, wv, lane);
    stage_half<3>(mat, wbase, xbase, 0, wv, lane);
    stage_half<0>(mat, wbase, xbase, 1, wv, lane);
    stage_half<1>(mat, wbase, xbase, 1, wv, lane);
    vmw<8>();
    bar(); sb0();

#pragma unroll 1
    for (int i = 0; i < 7; ++i) {
        ktile<0, true, true, 8, 8, true>(mat, wbase, xbase, 2 * i,     wv, lane, wm, wn, q, l15, acc);
        ktile<1, true, true, 8, 8, true>(mat, wbase, xbase, 2 * i + 1, wv, lane, wm, wn, q, l15, acc);
    }
    ktile<0, true,  false, 8, 4, true >(mat, wbase, xbase, 14, wv, lane, wm, wn, q, l15, acc);
    ktile<1, false, false, 0, 0, false>(mat, wbase, xbase, 15, wv, lane, wm, wn, q, l15, acc);

    __syncthreads();

    // C-write: +bias, bf16, write 4 combos' Qs/Ks into LDS (combo c = wm*2 + (wn>>1), 2048 units each)
    {
        unsigned short* m16 = (unsigned short*)mat;
        const int hglob = hg * 2 + wm;
#pragma unroll
        for (int rt = 0; rt < 8; ++rt) {
            const int mh0   = rt * 16 + q * 4;          // rows mh0..mh0+3 (within head's [Wq;Wk])
            const int d0    = mh0 & 63;
            const int kbase = (mh0 < 64) ? 0 : 1024;
            float bias4[4];
#pragma unroll
            for (int rr = 0; rr < 4; ++rr)
                bias4[rr] = (mh0 < 64) ? bq[hglob * D + d0 + rr] : bk[hglob * D + d0 + rr];
#pragma unroll
            for (int ct = 0; ct < 4; ++ct) {
                const int col = wn * 64 + ct * 16 + l15;
                const int bj  = col >> 7;
                const int s   = col & 127;
                const int c   = wm * 2 + bj;
                unsigned long long pv = 0;
#pragma unroll
                for (int rr = 0; rr < 4; ++rr)
                    pv |= (unsigned long long)f2bf(acc[rt][ct][rr] + bias4[rr]) << (16 * rr);
                const int unit = c * 2048 + kbase + s * 8 + ((d0 >> 3) ^ (s & 7));
                *(unsigned long long*)&m16[unit * 8 + (d0 & 7)] = pv;   // 8B-aligned (d0&7 in {0,4})
            }
        }
    }
    __syncthreads();

    // ---- pair-parallel epilogue: waves {2c,2c+1} own combo c; all combos concurrent ----
    const int ce   = ((wv >> 2) << 1) | ((wv >> 1) & 1);   // this wave's combo
    const int half = wv & 1;                               // s-row half within combo
    const int qb = ce * 2048;
    const int kb = ce * 2048 + 1024;
    const int bglob = bg * 2 + (ce & 1);
    const int hglob = hg * 2 + (ce >> 1);

    // phase 2: scores for s-rows [half*64, +64), all 128 t
    f32x4 p[4][8];
#pragma unroll
    for (int mt = 0; mt < 4; ++mt)
#pragma unroll
        for (int nt = 0; nt < 8; ++nt) p[mt][nt] = (f32x4){0.f, 0.f, 0.f, 0.f};
#pragma unroll
    for (int ks = 0; ks < 2; ++ks) {
        const int kcq = ks * 4 + q;
        bf16x8 a2[4], b2[8];
#pragma unroll
        for (int mt = 0; mt < 4; ++mt) {
            const int row = half * 64 + mt * 16 + l15;
            a2[mt] = *(const bf16x8*)&mat[qb + row * 8 + (kcq ^ (row & 7))];
        }
#pragma unroll
        for (int nt = 0; nt < 8; ++nt) {
            const int trow = nt * 16 + l15;
            b2[nt] = *(const bf16x8*)&mat[kb + trow * 8 + (kcq ^ (trow & 7))];
        }
#pragma unroll
        for (int mt = 0; mt < 4; ++mt)
#pragma unroll
            for (int nt = 0; nt < 8; ++nt)
                p[mt][nt] = __builtin_amdgcn_mfma_f32_16x16x32_bf16(a2[mt], b2[nt], p[mt][nt], 0, 0, 0);
    }

    // phases 3+4: softmax (no max-sub; scores ~N(0,1), clamp insurance) + fold Wo
    float pw[8];
#pragma unroll
    for (int nt = 0; nt < 8; ++nt) pw[nt] = 0.f;
#pragma unroll
    for (int mt = 0; mt < 4; ++mt) {
#pragma unroll
        for (int rr = 0; rr < 4; ++rr) {
            const int srow = half * 64 + mt * 16 + q * 4 + rr;
            float e[8];
            float l = 0.f;
#pragma unroll
            for (int nt = 0; nt < 8; ++nt) {
                e[nt] = __expf(fminf(p[mt][nt][rr] * 0.125f, 80.f));   // 1/TEMP = 1/8
                l += e[nt];
            }
#pragma unroll
            for (int off = 1; off < 16; off <<= 1) l += __shfl_xor(l, off);
            const float cw = Wo[srow] / l;
#pragma unroll
            for (int nt = 0; nt < 8; ++nt) pw[nt] = fmaf(cw, e[nt], pw[nt]);
        }
    }
#pragma unroll
    for (int nt = 0; nt < 8; ++nt) {
        pw[nt] += __shfl_xor(pw[nt], 16);
        pw[nt] += __shfl_xor(pw[nt], 32);
    }
    if (q == 0) {
#pragma unroll
        for (int nt = 0; nt < 8; ++nt) wpart[wv * 128 + nt * 16 + l15] = pw[nt];
    }
    __syncthreads();

    // phase 5: out[bglob, hglob*64+dd] = sum_t w[t] * x[bglob, hglob*64+dd, t] + bo
    {
        const int local = half * 64 + lane;      // [0,128) within combo
        const int dd    = local >> 1;
        const int part  = local & 1;
        const float* w0 = wpart + 2 * ce * 128;
        const float* w1 = wpart + (2 * ce + 1) * 128;
        const float4* xv = (const float4*)(x + (size_t)bglob * (F * S)
                                             + (size_t)(hglob * D + dd) * S + part * 64);
        float a5 = 0.f;
#pragma unroll
        for (int j = 0; j < 16; ++j) {
            float4 vv = xv[j];
            const int t = part * 64 + j * 4;
            a5 = fmaf(w0[t + 0] + w1[t + 0], vv.x, a5);
            a5 = fmaf(w0[t + 1] + w1[t + 1], vv.y, a5);
            a5 = fmaf(w0[t + 2] + w1[t + 2], vv.z, a5);
            a5 = fmaf(w0[t + 3] + w1[t + 3], vv.w, a5);
        }
        a5 += __shfl_xor(a5, 1);
        if (part == 0) out[(size_t)bglob * F + hglob * D + dd] = a5 + bo[0];
    }
}

// ---------------- fallback (self-contained) if ws too small ----------------
struct SmemT {
    uint4 mat[2048];
    float wpart[4][S];
    float wfin[S];
};

__launch_bounds__(256, 4)
__global__ void attn_fallback(const float* __restrict__ x,
                              const float* __restrict__ Wq,
                              const float* __restrict__ bq,
                              const float* __restrict__ Wk,
                              const float* __restrict__ bk,
                              const float* __restrict__ Wo,
                              const float* __restrict__ bo,
                              float* __restrict__ out)
{
    __shared__ SmemT sm;
    const int tid  = threadIdx.x;
    const int lane = tid & 63;
    const int wv   = tid >> 6;
    const int l15  = lane & 15;
    const int q    = lane >> 4;

    const int g    = blockIdx.x;
    const int xcd  = g & 7;
    const int slot = g >> 3;
    const int hg   = slot >> 7;
    const int r0   = slot & 127;
    const int b    = xcd * 32 + (r0 >> 2);
    const int h    = hg * 4 + (r0 & 3);

    const float* xb  = x  + (size_t)b * (F * S);
    const float* wqh = Wq + (size_t)h * D * F;
    const float* wkh = Wk + (size_t)h * D * F;

    const int m0 = (wv & 1) * 64;
    const int n0 = (wv >> 1) * 64;

    f32x4 acc[4][4];
#pragma unroll
    for (int mt = 0; mt < 4; ++mt)
#pragma unroll
        for (int nt = 0; nt < 4; ++nt) acc[mt][nt] = (f32x4){0.f, 0.f, 0.f, 0.f};

    const int mq  = tid >> 2;
    const int kq  = tid & 3;
    const int s0x = (tid & 63) * 2;
    const int iq  = tid >> 6;

    for (int ch = 0; ch < NCHUNK; ++ch) {
        const int c0 = ch * CK;
        __syncthreads();
        {
            const int key = mq & 7;
            float f[16];
            const float4* srcq = (const float4*)(wqh + (size_t)mq * F + (c0 + kq * 16));
#pragma unroll
            for (int j = 0; j < 4; ++j) {
                float4 v = srcq[j];
                f[4*j] = v.x; f[4*j+1] = v.y; f[4*j+2] = v.z; f[4*j+3] = v.w;
            }
            sm.mat[mq * 8 + ((kq * 2    ) ^ key)] = pack8(f);
            sm.mat[mq * 8 + ((kq * 2 + 1) ^ key)] = pack8(f + 8);
            const float4* srck = (const float4*)(wkh + (size_t)mq * F + (c0 + kq * 16));
#pragma unroll
            for (int j = 0; j < 4; ++j) {
                float4 v = srck[j];
                f[4*j] = v.x; f[4*j+1] = v.y; f[4*j+2] = v.z; f[4*j+3] = v.w;
            }
            sm.mat[(64 + mq) * 8 + ((kq * 2    ) ^ key)] = pack8(f);
            sm.mat[(64 + mq) * 8 + ((kq * 2 + 1) ^ key)] = pack8(f + 8);
        }
        {
            const float* src = xb + (size_t)(c0 + iq * 16) * S + s0x;
            float fa[8], fb[8];
#pragma unroll
            for (int grp = 0; grp < 2; ++grp) {
#pragma unroll
                for (int j = 0; j < 8; ++j) {
                    float2 v = *(const float2*)(src + (size_t)(grp * 8 + j) * S);
                    fa[j] = v.x; fb[j] = v.y;
                }
                const int kc = iq * 2 + grp;
                sm.mat[1024 + (s0x    ) * 8 + (kc ^ ((s0x    ) & 7))] = pack8(fa);
                sm.mat[1024 + (s0x + 1) * 8 + (kc ^ ((s0x + 1) & 7))] = pack8(fb);
            }
        }
        __syncthreads();
#pragma unroll
        for (int ks = 0; ks < 2; ++ks) {
            bf16x8 af[4], br[4];
#pragma unroll
            for (int mt = 0; mt < 4; ++mt) {
                const int row = m0 + mt * 16 + l15;
                af[mt] = *(const bf16x8*)&sm.mat[row * 8 + ((ks * 4 + q) ^ (row & 7))];
            }
#pragma unroll
            for (int nt = 0; nt < 4; ++nt) {
                const int row = n0 + nt * 16 + l15;
                br[nt] = *(const bf16x8*)&sm.mat[1024 + row * 8 + ((ks * 4 + q) ^ (row & 7))];
            }
#pragma unroll
            for (int mt = 0; mt < 4; ++mt)
#pragma unroll
                for (int nt = 0; nt < 4; ++nt)
                    acc[mt][nt] = __builtin_amdgcn_mfma_f32_16x16x32_bf16(
                        af[mt], br[nt], acc[mt][nt], 0, 0, 0);
        }
    }

    __syncthreads();
    {
        unsigned short* m16 = (unsigned short*)sm.mat;
#pragma unroll
        for (int mt = 0; mt < 4; ++mt) {
#pragma unroll
            for (int rr = 0; rr < 4; ++rr) {
                const int m = m0 + mt * 16 + q * 4 + rr;
                const int d = m & 63;
                const float bias = (m < 64) ? bq[h * D + d] : bk[h * D + d];
                const int base = (m < 64) ? 0 : 8192;
#pragma unroll
                for (int nt = 0; nt < 4; ++nt) {
                    const int s = n0 + nt * 16 + l15;
                    const float v = acc[mt][nt][rr] + bias;
                    const int unit = s * 8 + (((d >> 3)) ^ (s & 7));
                    m16[base + unit * 8 + (d & 7)] = f2bf(v);
                }
            }
        }
    }
    __syncthreads();

    f32x4 p[2][8];
#pragma unroll
    for (int mt = 0; mt < 2; ++mt)
#pragma unroll
        for (int nt = 0; nt < 8; ++nt) p[mt][nt] = (f32x4){0.f, 0.f, 0.f, 0.f};

#pragma unroll
    for (int ks = 0; ks < 2; ++ks) {
        bf16x8 a2[2], b2[8];
#pragma unroll
        for (int mt = 0; mt < 2; ++mt) {
            const int row = wv * 32 + mt * 16 + l15;
            a2[mt] = *(const bf16x8*)&sm.mat[row * 8 + ((ks * 4 + q) ^ (row & 7))];
        }
#pragma unroll
        for (int nt = 0; nt < 8; ++nt) {
            const int row = nt * 16 + l15;
            b2[nt] = *(const bf16x8*)&sm.mat[1024 + row * 8 + ((ks * 4 + q) ^ (row & 7))];
        }
#pragma unroll
        for (int mt = 0; mt < 2; ++mt)
#pragma unroll
            for (int nt = 0; nt < 8; ++nt)
                p[mt][nt] = __builtin_amdgcn_mfma_f32_16x16x32_bf16(a2[mt], b2[nt], p[mt][nt], 0, 0, 0);
    }

    float pw[8];
#pragma unroll
    for (int nt = 0; nt < 8; ++nt) pw[nt] = 0.f;

#pragma unroll
    for (int mt = 0; mt < 2; ++mt) {
#pragma unroll
        for (int rr = 0; rr < 4; ++rr) {
            const int srow = wv * 32 + mt * 16 + q * 4 + rr;
            float mx = p[mt][0][rr];
#pragma unroll
            for (int nt = 1; nt < 8; ++nt) mx = fmaxf(mx, p[mt][nt][rr]);
#pragma unroll
            for (int off = 1; off < 16; off <<= 1) mx = fmaxf(mx, __shfl_xor(mx, off));
            float e[8];
            float l = 0.f;
#pragma unroll
            for (int nt = 0; nt < 8; ++nt) {
                e[nt] = __expf((p[mt][nt][rr] - mx) * 0.125f);
                l += e[nt];
            }
#pragma unroll
            for (int off = 1; off < 16; off <<= 1) l += __shfl_xor(l, off);
            const float c = Wo[srow] / l;
#pragma unroll
            for (int nt = 0; nt < 8; ++nt) pw[nt] = fmaf(c, e[nt], pw[nt]);
        }
    }
#pragma unroll
    for (int nt = 0; nt < 8; ++nt) {
        pw[nt] += __shfl_xor(pw[nt], 16);
        pw[nt] += __shfl_xor(pw[nt], 32);
    }
    if (q == 0) {
#pragma unroll
        for (int nt = 0; nt < 8; ++nt) sm.wpart[wv][nt * 16 + l15] = pw[nt];
    }
    __syncthreads();
    if (tid < S)
        sm.wfin[tid] = sm.wpart[0][tid] + sm.wpart[1][tid] + sm.wpart[2][tid] + sm.wpart[3][tid];
    __syncthreads();

    {
        const int dd   = tid >> 2;
        const int part = tid & 3;
        const float* xv = xb + (size_t)(h * D + dd) * S + part * 32;
        float a5 = 0.f;
#pragma unroll 8
        for (int t = 0; t < 32; ++t) a5 = fmaf(sm.wfin[part * 32 + t], xv[t], a5);
        a5 += __shfl_xor(a5, 1);
        a5 += __shfl_xor(a5, 2);
        if (part == 0) out[(size_t)b * F + h * D + dd] = a5 + bo[0];
    }
}

extern "C" void kernel_launch(void* const* d_in, const int* in_sizes, int n_in,
                              void* d_out, int out_size, void* d_ws, size_t ws_size,
                              hipStream_t stream) {
    const float* x  = (const float*)d_in[0];
    const float* Wq = (const float*)d_in[1];
    const float* bq = (const float*)d_in[2];
    const float* Wk = (const float*)d_in[3];
    const float* bk = (const float*)d_in[4];
    const float* Wo = (const float*)d_in[5];
    const float* bo = (const float*)d_in[6];
    float* out = (float*)d_out;

    if (ws_size >= WS_NEED) {
        uint4* xsp = (uint4*)d_ws;
        uint4* wbp = (uint4*)((char*)d_ws + XS_UNITS * 16);
        static bool attr_done = false;
        if (!attr_done) {
            (void)hipFuncSetAttribute(reinterpret_cast<const void*>(attn_main),
                                      hipFuncAttributeMaxDynamicSharedMemorySize, MAIN_LDS_BYTES);
            attr_done = true;
        }
        prep<<<dim3(1024 + 64), dim3(256), 0, stream>>>(x, Wq, Wk, xsp, wbp);
        attn_main<<<dim3(1024), dim3(512), MAIN_LDS_BYTES, stream>>>(x, xsp, wbp, bq, bk, Wo, bo, out);
    } else {
        attn_fallback<<<dim3(256 * H), dim3(256), 0, stream>>>(x, Wq, bq, Wk, bk, Wo, bo, out);
    }
}

// Round 4
// 352.991 us; speedup vs baseline: 1.1258x; 1.1258x over previous
//
#include <hip/hip_runtime.h>

#define F 1024
#define S 128
#define H 16
#define D 64
#define CK 64        // K per tile (BK)
#define NCHUNK 16    // 1024 / 64

typedef short bf16x8 __attribute__((ext_vector_type(8)));
typedef float f32x4  __attribute__((ext_vector_type(4)));

// ws: xs2[128 bg][16 ch][2048 units] (B-tiles: rows = 2 batches' s, k-major)
//     wb2[ 8 hg][16 ch][2048 units] (A-tiles: rows = 2 heads' [Wq;Wk], k-major)
// unit(kc,row) = kc*256 + row ; kc in [0,8) (8 bf16 of k each), row in [0,256)
#define XS_UNITS ((size_t)128 * NCHUNK * 2048)
#define WB_UNITS ((size_t)8 * NCHUNK * 2048)
#define WS_NEED ((XS_UNITS + WB_UNITS) * 16)

#define MAIN_LDS_BYTES (8192 * 16 + 8 * 128 * 4 + 128 * 4)

__device__ __forceinline__ unsigned short f2bf(float f) {
    unsigned u = __float_as_uint(f);
    u += 0x7fffu + ((u >> 16) & 1u);   // round-to-nearest-even
    return (unsigned short)(u >> 16);
}

__device__ __forceinline__ uint4 pack8(const float* f) {
    uint4 u;
    u.x = (unsigned)f2bf(f[0]) | ((unsigned)f2bf(f[1]) << 16);
    u.y = (unsigned)f2bf(f[2]) | ((unsigned)f2bf(f[3]) << 16);
    u.z = (unsigned)f2bf(f[4]) | ((unsigned)f2bf(f[5]) << 16);
    u.w = (unsigned)f2bf(f[6]) | ((unsigned)f2bf(f[7]) << 16);
    return u;
}

typedef __attribute__((address_space(1))) const unsigned int as1_u32;
typedef __attribute__((address_space(3))) unsigned int as3_u32;

__device__ __forceinline__ void async_cp16(const uint4* g, uint4* l) {
    __builtin_amdgcn_global_load_lds((as1_u32*)g, (as3_u32*)l, 16, 0, 0);
}

__device__ __forceinline__ void bar()   { __builtin_amdgcn_s_barrier(); }
__device__ __forceinline__ void sb0()   { __builtin_amdgcn_sched_barrier(0); }
__device__ __forceinline__ void lgkm0() { asm volatile("s_waitcnt lgkmcnt(0)"); }

template<int N> __device__ __forceinline__ void vmw() {
    asm volatile("s_waitcnt vmcnt(%0)" :: "n"(N));
}

// ---------------- prep: fp32 -> bf16, k-major tiles (round-2 structure: 1 chunk/block, 16 blocks/CU) ----------------
__global__ void prep(const float* __restrict__ x,
                     const float* __restrict__ Wq,
                     const float* __restrict__ Wk,
                     uint4* __restrict__ xs,
                     uint4* __restrict__ wb)
{
    __shared__ float4 t4[64 * 33];      // row stride 33 float4 = 132 floats (conflict-free)
    const int tid = threadIdx.x;
    const int blk = blockIdx.x;
    if (blk < 4096) {
        // x tile: (b, ch) -> 64 i-rows x 128 s, emitted as unit = kc*256 + (b&1)*128 + s
        const int b = blk >> 4, ch = blk & 15;
        const float4* src = (const float4*)(x + ((size_t)b * F + ch * CK) * S);
        float4 v[8];
#pragma unroll
        for (int j = 0; j < 8; ++j) v[j] = src[tid + j * 256];
#pragma unroll
        for (int j = 0; j < 8; ++j) {
            const int e4 = tid + j * 256;
            t4[(e4 >> 5) * 33 + (e4 & 31)] = v[j];   // float4 store
        }
        __syncthreads();
        const float* tile = (const float*)t4;
        uint4* dst = xs + ((size_t)(b >> 1) * NCHUNK + ch) * 2048 + (b & 1) * 128;
#pragma unroll
        for (int j = 0; j < 4; ++j) {
            const int u  = tid + j * 256;
            const int kc = u >> 7;
            const int s  = u & 127;
            float f[8];
#pragma unroll
            for (int jj = 0; jj < 8; ++jj) f[jj] = tile[(kc * 8 + jj) * 132 + s];
            dst[kc * 256 + s] = pack8(f);
        }
    } else {
        // W tile: (h, ch) -> unit = kc*256 + (h&1)*128 + m ; m<64 -> Wq row, else Wk row
        const int blk2 = blk - 4096;
        const int h = blk2 >> 4, ch = blk2 & 15;
        uint4* dst = wb + ((size_t)(h >> 1) * NCHUNK + ch) * 2048 + (h & 1) * 128;
#pragma unroll
        for (int j = 0; j < 4; ++j) {
            const int u  = tid + j * 256;
            const int kc = u >> 7;
            const int m  = u & 127;
            const float* srcp = (m < 64)
                ? (Wq + (size_t)(h * D + m) * F + ch * CK + kc * 8)
                : (Wk + (size_t)(h * D + m - 64) * F + ch * CK + kc * 8);
            float f[8];
            float4 a = ((const float4*)srcp)[0];
            float4 c = ((const float4*)srcp)[1];
            f[0] = a.x; f[1] = a.y; f[2] = a.z; f[3] = a.w;
            f[4] = c.x; f[5] = c.y; f[6] = c.z; f[7] = c.w;
            dst[kc * 256 + m] = pack8(f);
        }
    }
}

// ---------------- main kernel helpers ----------------
__device__ __forceinline__ void read4(const uint4* mat, int base, bf16x8 (&r)[4]) {
    r[0] = *(const bf16x8*)&mat[base];
    r[1] = *(const bf16x8*)&mat[base + 16];
    r[2] = *(const bf16x8*)&mat[base + 32];
    r[3] = *(const bf16x8*)&mat[base + 48];
}

template<int RB>
__device__ __forceinline__ void mfma16(f32x4 (&acc)[8][4], const bf16x8 (&af)[4], const bf16x8 (&br)[4]) {
#pragma unroll
    for (int mt = 0; mt < 4; ++mt)
#pragma unroll
        for (int nt = 0; nt < 4; ++nt)
            acc[RB + mt][nt] = __builtin_amdgcn_mfma_f32_16x16x32_bf16(af[mt], br[nt], acc[RB + mt][nt], 0, 0, 0);
}

// half-tiles (16 KB each): 0 = A.ks0, 1 = B.ks0, 2 = A.ks1, 3 = B.ks1
template<int HALF>
__device__ __forceinline__ void stage_half(uint4* mat, const uint4* wbase, const uint4* xbase,
                                           int tgt, int wv, int lane) {
    const int bufb = (tgt & 1) * 4096;
    const uint4* g;
    int l;
    if constexpr (HALF == 0)      { g = wbase + (size_t)tgt * 2048;        l = bufb;        }
    else if constexpr (HALF == 1) { g = xbase + (size_t)tgt * 2048;        l = bufb + 2048; }
    else if constexpr (HALF == 2) { g = wbase + (size_t)tgt * 2048 + 1024; l = bufb + 1024; }
    else                          { g = xbase + (size_t)tgt * 2048 + 1024; l = bufb + 3072; }
    async_cp16(g + wv * 128 + lane,      &mat[l + wv * 128]);
    async_cp16(g + wv * 128 + 64 + lane, &mat[l + wv * 128 + 64]);
}

// One K-tile (BK=64): 4 phases {ds_read | 1 half-tile DMA | barrier | MFMA}.
// Counted vmcnt ledger: W1 (after ph2) completes ks1(t); W2 (after ph4) completes ks0(t+1).
template<int CUR, bool I1, bool I2, int W1, int W2, bool DW2>
__device__ __forceinline__ void ktile(uint4* mat, const uint4* wbase, const uint4* xbase,
                                      int t, int wv, int lane, int wm, int wn, int q, int l15,
                                      f32x4 (&acc)[8][4])
{
    bf16x8 af[4], br[4];
    const int abase = CUR * 4096 + wm * 128 + l15;
    const int bbase = CUR * 4096 + 2048 + wn * 64 + l15;
    const int kq = q * 256;
    // ph1: ks0, row-half 0
    read4(mat, abase + kq, af);
    read4(mat, bbase + kq, br);
    if constexpr (I1) stage_half<2>(mat, wbase, xbase, t + 1, wv, lane);
    bar(); lgkm0(); sb0();
    __builtin_amdgcn_s_setprio(1); mfma16<0>(acc, af, br); __builtin_amdgcn_s_setprio(0);
    bar(); sb0();
    // ph2: ks0, row-half 1 (br reused from regs)
    read4(mat, abase + kq + 64, af);
    if constexpr (I1) stage_half<3>(mat, wbase, xbase, t + 1, wv, lane);
    bar(); lgkm0(); sb0();
    __builtin_amdgcn_s_setprio(1); mfma16<4>(acc, af, br); __builtin_amdgcn_s_setprio(0);
    vmw<W1>(); bar(); sb0();
    // ph3: ks1, row-half 0
    read4(mat, abase + kq + 1024, af);
    read4(mat, bbase + kq + 1024, br);
    if constexpr (I2) stage_half<0>(mat, wbase, xbase, t + 2, wv, lane);
    bar(); lgkm0(); sb0();
    __builtin_amdgcn_s_setprio(1); mfma16<0>(acc, af, br); __builtin_amdgcn_s_setprio(0);
    bar(); sb0();
    // ph4: ks1, row-half 1
    read4(mat, abase + kq + 1024 + 64, af);
    if constexpr (I2) stage_half<1>(mat, wbase, xbase, t + 2, wv, lane);
    bar(); lgkm0(); sb0();
    __builtin_amdgcn_s_setprio(1); mfma16<4>(acc, af, br); __builtin_amdgcn_s_setprio(0);
    if constexpr (DW2) { vmw<W2>(); bar(); sb0(); }
}

// ---------------- main: 256x256x1024 GEMM (2 heads x 2 batches) + pair-parallel attention epilogue ----------------
__launch_bounds__(512, 2)
__global__ void attn_main(const float* __restrict__ x,
                          const uint4* __restrict__ xs,
                          const uint4* __restrict__ wb,
                          const float* __restrict__ bq,
                          const float* __restrict__ bk,
                          const float* __restrict__ Wo,
                          const float* __restrict__ bo,
                          float* __restrict__ out)
{
    (void)x;
    extern __shared__ char smraw[];
    uint4* mat   = (uint4*)smraw;                       // 8192 units = 2 x (A 2048 + B 2048)
    float* wpart = (float*)(smraw + 8192 * 16);         // [8][128]

    const int tid  = threadIdx.x;
    const int lane = tid & 63;
    const int wv   = tid >> 6;
    const int l15  = lane & 15;
    const int q    = lane >> 4;
    const int wm   = wv >> 2;      // 2 waves rows
    const int wn   = wv & 3;       // 4 waves cols

    // XCD-aware swizzle: 1024 blocks, 8 XCDs; per XCD 16 bg x 8 hg
    const int g    = blockIdx.x;
    const int xcd  = g & 7;
    const int slot = g >> 3;
    const int bg   = xcd * 16 + (slot & 15);   // batch-pair [0,128)
    const int hg   = slot >> 4;                // head-pair  [0,8)

    const uint4* wbase = wb + (size_t)hg * NCHUNK * 2048;
    const uint4* xbase = xs + (size_t)bg * NCHUNK * 2048;

    f32x4 acc[8][4];
#pragma unroll
    for (int mi = 0; mi < 8; ++mi)
#pragma unroll
        for (int ni = 0; ni < 4; ++ni) acc[mi][ni] = (f32x4){0.f, 0.f, 0.f, 0.f};

    // prologue: tile0 all 4 halves + tile1 ks0 halves; wait oldest 4 loads (tile0.ks0)
    stage_half<0>(mat, wbase, xbase, 0, wv, lane);
    stage_half<1>(mat, wbase, xbase, 0, wv, lane);
    stage_half<2>(mat, wbase, xbase, 0, wv, lane);
    stage_half<3>(mat, wbase, xbase, 0, wv, lane);
    stage_half<0>(mat, wbase, xbase, 1, wv, lane);
    stage_half<1>(mat, wbase, xbase, 1, wv, lane);
    vmw<8>();
    bar(); sb0();

#pragma unroll 1
    for (int i = 0; i < 7; ++i) {
        ktile<0, true, true, 8, 8, true>(mat, wbase, xbase, 2 * i,     wv, lane, wm, wn, q, l15, acc);
        ktile<1, true, true, 8, 8, true>(mat, wbase, xbase, 2 * i + 1, wv, lane, wm, wn, q, l15, acc);
    }
    ktile<0, true,  false, 8, 4, true >(mat, wbase, xbase, 14, wv, lane, wm, wn, q, l15, acc);
    ktile<1, false, false, 0, 0, false>(mat, wbase, xbase, 15, wv, lane, wm, wn, q, l15, acc);

    __syncthreads();

    // C-write: +bias, bf16, write 4 combos' Qs/Ks into LDS (combo c = wm*2 + (col>>7), 2048 units each)
    {
        unsigned short* m16 = (unsigned short*)mat;
        const int hglobw = hg * 2 + wm;
#pragma unroll
        for (int rt = 0; rt < 8; ++rt) {
            const int mh0   = rt * 16 + q * 4;          // rows mh0..mh0+3 (within head's [Wq;Wk])
            const int d0    = mh0 & 63;
            const int kbase = (mh0 < 64) ? 0 : 1024;
            float bias4[4];
#pragma unroll
            for (int rr = 0; rr < 4; ++rr)
                bias4[rr] = (mh0 < 64) ? bq[hglobw * D + d0 + rr] : bk[hglobw * D + d0 + rr];
#pragma unroll
            for (int ct = 0; ct < 4; ++ct) {
                const int col = wn * 64 + ct * 16 + l15;
                const int bj  = col >> 7;
                const int s   = col & 127;
                const int c   = wm * 2 + bj;
                unsigned long long pv = 0;
#pragma unroll
                for (int rr = 0; rr < 4; ++rr)
                    pv |= (unsigned long long)f2bf(acc[rt][ct][rr] + bias4[rr]) << (16 * rr);
                const int unit = c * 2048 + kbase + s * 8 + ((d0 >> 3) ^ (s & 7));
                *(unsigned long long*)&m16[unit * 8 + (d0 & 7)] = pv;   // 8B-aligned (d0&7 in {0,4})
            }
        }
    }
    __syncthreads();

    // ---- pair-parallel epilogue: waves {2c,2c+1} own combo c; all combos concurrent ----
    const int ce   = ((wv >> 2) << 1) | ((wv >> 1) & 1);   // this wave's combo
    const int half = wv & 1;                               // s-row half within combo
    const int qb = ce * 2048;
    const int kb = ce * 2048 + 1024;
    const int bglob = bg * 2 + (ce & 1);
    const int hglob = hg * 2 + (ce >> 1);

    // phase 2: scores for s-rows [half*64, +64), all 128 t
    f32x4 p[4][8];
#pragma unroll
    for (int mt = 0; mt < 4; ++mt)
#pragma unroll
        for (int nt = 0; nt < 8; ++nt) p[mt][nt] = (f32x4){0.f, 0.f, 0.f, 0.f};
#pragma unroll
    for (int ks = 0; ks < 2; ++ks) {
        const int kcq = ks * 4 + q;
        bf16x8 a2[4], b2[8];
#pragma unroll
        for (int mt = 0; mt < 4; ++mt) {
            const int row = half * 64 + mt * 16 + l15;
            a2[mt] = *(const bf16x8*)&mat[qb + row * 8 + (kcq ^ (row & 7))];
        }
#pragma unroll
        for (int nt = 0; nt < 8; ++nt) {
            const int trow = nt * 16 + l15;
            b2[nt] = *(const bf16x8*)&mat[kb + trow * 8 + (kcq ^ (trow & 7))];
        }
#pragma unroll
        for (int mt = 0; mt < 4; ++mt)
#pragma unroll
            for (int nt = 0; nt < 8; ++nt)
                p[mt][nt] = __builtin_amdgcn_mfma_f32_16x16x32_bf16(a2[mt], b2[nt], p[mt][nt], 0, 0, 0);
    }

    // phase-5 loads issued EARLY (hidden under softmax): coalesced uint4 from xs, chunk ch = hglob
    // lane ell = half*64+lane: kc = ell>>4 (8 k-subchunks = 64 i), sg = ell&15 (16 s-groups of 8)
    const int ell = half * 64 + lane;
    const int kc5 = ell >> 4;
    const int sg5 = ell & 15;
    const uint4* xsrc = xbase + (size_t)hglob * 2048 + kc5 * 256 + (ce & 1) * 128 + sg5 * 8;
    uint4 xu[8];
#pragma unroll
    for (int jj = 0; jj < 8; ++jj) xu[jj] = xsrc[jj];

    // phases 3+4: softmax (no max-sub; scores ~N(0,1), clamp insurance) + fold Wo
    float pw[8];
#pragma unroll
    for (int nt = 0; nt < 8; ++nt) pw[nt] = 0.f;
#pragma unroll
    for (int mt = 0; mt < 4; ++mt) {
#pragma unroll
        for (int rr = 0; rr < 4; ++rr) {
            const int srow = half * 64 + mt * 16 + q * 4 + rr;
            float e[8];
            float l = 0.f;
#pragma unroll
            for (int nt = 0; nt < 8; ++nt) {
                e[nt] = __expf(fminf(p[mt][nt][rr] * 0.125f, 80.f));   // 1/TEMP = 1/8
                l += e[nt];
            }
#pragma unroll
            for (int off = 1; off < 16; off <<= 1) l += __shfl_xor(l, off);
            const float cw = Wo[srow] / l;
#pragma unroll
            for (int nt = 0; nt < 8; ++nt) pw[nt] = fmaf(cw, e[nt], pw[nt]);
        }
    }
#pragma unroll
    for (int nt = 0; nt < 8; ++nt) {
        pw[nt] += __shfl_xor(pw[nt], 16);
        pw[nt] += __shfl_xor(pw[nt], 32);
    }
    if (q == 0) {
#pragma unroll
        for (int nt = 0; nt < 8; ++nt) wpart[wv * 128 + nt * 16 + l15] = pw[nt];
    }
    __syncthreads();

    // phase 5: out[bglob, hglob*64 + kc5*8 + e] = sum_s w[s] * x_bf16 + bo  (x from regs)
    {
        const float* w0 = wpart + 2 * ce * 128;
        const float* w1 = w0 + 128;
        float acc8[8];
#pragma unroll
        for (int e = 0; e < 8; ++e) acc8[e] = 0.f;
#pragma unroll
        for (int jj = 0; jj < 8; ++jj) {
            const int s = sg5 * 8 + jj;
            const float w = w0[s] + w1[s];
            const unsigned* du = (const unsigned*)&xu[jj];
#pragma unroll
            for (int dw = 0; dw < 4; ++dw) {
                const unsigned v = du[dw];
                acc8[dw * 2 + 0] = fmaf(__uint_as_float(v << 16), w, acc8[dw * 2 + 0]);
                acc8[dw * 2 + 1] = fmaf(__uint_as_float(v & 0xffff0000u), w, acc8[dw * 2 + 1]);
            }
        }
        // reduce over the 16 s-groups (lanes sharing kc5)
#pragma unroll
        for (int e = 0; e < 8; ++e) {
#pragma unroll
            for (int off = 1; off < 16; off <<= 1)
                acc8[e] += __shfl_xor(acc8[e], off);
        }
        if (sg5 < 8)
            out[(size_t)bglob * F + hglob * D + kc5 * 8 + sg5] = acc8[sg5] + bo[0];
    }
}

// ---------------- fallback (self-contained) if ws too small ----------------
struct SmemT {
    uint4 mat[2048];
    float wpart[4][S];
    float wfin[S];
};

__launch_bounds__(256, 4)
__global__ void attn_fallback(const float* __restrict__ x,
                              const float* __restrict__ Wq,
                              const float* __restrict__ bq,
                              const float* __restrict__ Wk,
                              const float* __restrict__ bk,
                              const float* __restrict__ Wo,
                              const float* __restrict__ bo,
                              float* __restrict__ out)
{
    __shared__ SmemT sm;
    const int tid  = threadIdx.x;
    const int lane = tid & 63;
    const int wv   = tid >> 6;
    const int l15  = lane & 15;
    const int q    = lane >> 4;

    const int g    = blockIdx.x;
    const int xcd  = g & 7;
    const int slot = g >> 3;
    const int hg   = slot >> 7;
    const int r0   = slot & 127;
    const int b    = xcd * 32 + (r0 >> 2);
    const int h    = hg * 4 + (r0 & 3);

    const float* xb  = x  + (size_t)b * (F * S);
    const float* wqh = Wq + (size_t)h * D * F;
    const float* wkh = Wk + (size_t)h * D * F;

    const int m0 = (wv & 1) * 64;
    const int n0 = (wv >> 1) * 64;

    f32x4 acc[4][4];
#pragma unroll
    for (int mt = 0; mt < 4; ++mt)
#pragma unroll
        for (int nt = 0; nt < 4; ++nt) acc[mt][nt] = (f32x4){0.f, 0.f, 0.f, 0.f};

    const int mq  = tid >> 2;
    const int kq  = tid & 3;
    const int s0x = (tid & 63) * 2;
    const int iq  = tid >> 6;

    for (int ch = 0; ch < NCHUNK; ++ch) {
        const int c0 = ch * CK;
        __syncthreads();
        {
            const int key = mq & 7;
            float f[16];
            const float4* srcq = (const float4*)(wqh + (size_t)mq * F + (c0 + kq * 16));
#pragma unroll
            for (int j = 0; j < 4; ++j) {
                float4 v = srcq[j];
                f[4*j] = v.x; f[4*j+1] = v.y; f[4*j+2] = v.z; f[4*j+3] = v.w;
            }
            sm.mat[mq * 8 + ((kq * 2    ) ^ key)] = pack8(f);
            sm.mat[mq * 8 + ((kq * 2 + 1) ^ key)] = pack8(f + 8);
            const float4* srck = (const float4*)(wkh + (size_t)mq * F + (c0 + kq * 16));
#pragma unroll
            for (int j = 0; j < 4; ++j) {
                float4 v = srck[j];
                f[4*j] = v.x; f[4*j+1] = v.y; f[4*j+2] = v.z; f[4*j+3] = v.w;
            }
            sm.mat[(64 + mq) * 8 + ((kq * 2    ) ^ key)] = pack8(f);
            sm.mat[(64 + mq) * 8 + ((kq * 2 + 1) ^ key)] = pack8(f + 8);
        }
        {
            const float* src = xb + (size_t)(c0 + iq * 16) * S + s0x;
            float fa[8], fb[8];
#pragma unroll
            for (int grp = 0; grp < 2; ++grp) {
#pragma unroll
                for (int j = 0; j < 8; ++j) {
                    float2 v = *(const float2*)(src + (size_t)(grp * 8 + j) * S);
                    fa[j] = v.x; fb[j] = v.y;
                }
                const int kc = iq * 2 + grp;
                sm.mat[1024 + (s0x    ) * 8 + (kc ^ ((s0x    ) & 7))] = pack8(fa);
                sm.mat[1024 + (s0x + 1) * 8 + (kc ^ ((s0x + 1) & 7))] = pack8(fb);
            }
        }
        __syncthreads();
#pragma unroll
        for (int ks = 0; ks < 2; ++ks) {
            bf16x8 af[4], br[4];
#pragma unroll
            for (int mt = 0; mt < 4; ++mt) {
                const int row = m0 + mt * 16 + l15;
                af[mt] = *(const bf16x8*)&sm.mat[row * 8 + ((ks * 4 + q) ^ (row & 7))];
            }
#pragma unroll
            for (int nt = 0; nt < 4; ++nt) {
                const int row = n0 + nt * 16 + l15;
                br[nt] = *(const bf16x8*)&sm.mat[1024 + row * 8 + ((ks * 4 + q) ^ (row & 7))];
            }
#pragma unroll
            for (int mt = 0; mt < 4; ++mt)
#pragma unroll
                for (int nt = 0; nt < 4; ++nt)
                    acc[mt][nt] = __builtin_amdgcn_mfma_f32_16x16x32_bf16(
                        af[mt], br[nt], acc[mt][nt], 0, 0, 0);
        }
    }

    __syncthreads();
    {
        unsigned short* m16 = (unsigned short*)sm.mat;
#pragma unroll
        for (int mt = 0; mt < 4; ++mt) {
#pragma unroll
            for (int rr = 0; rr < 4; ++rr) {
                const int m = m0 + mt * 16 + q * 4 + rr;
                const int d = m & 63;
                const float bias = (m < 64) ? bq[h * D + d] : bk[h * D + d];
                const int base = (m < 64) ? 0 : 8192;
#pragma unroll
                for (int nt = 0; nt < 4; ++nt) {
                    const int s = n0 + nt * 16 + l15;
                    const float v = acc[mt][nt][rr] + bias;
                    const int unit = s * 8 + (((d >> 3)) ^ (s & 7));
                    m16[base + unit * 8 + (d & 7)] = f2bf(v);
                }
            }
        }
    }
    __syncthreads();

    f32x4 p[2][8];
#pragma unroll
    for (int mt = 0; mt < 2; ++mt)
#pragma unroll
        for (int nt = 0; nt < 8; ++nt) p[mt][nt] = (f32x4){0.f, 0.f, 0.f, 0.f};

#pragma unroll
    for (int ks = 0; ks < 2; ++ks) {
        bf16x8 a2[2], b2[8];
#pragma unroll
        for (int mt = 0; mt < 2; ++mt) {
            const int row = wv * 32 + mt * 16 + l15;
            a2[mt] = *(const bf16x8*)&sm.mat[row * 8 + ((ks * 4 + q) ^ (row & 7))];
        }
#pragma unroll
        for (int nt = 0; nt < 8; ++nt) {
            const int row = nt * 16 + l15;
            b2[nt] = *(const bf16x8*)&sm.mat[1024 + row * 8 + ((ks * 4 + q) ^ (row & 7))];
        }
#pragma unroll
        for (int mt = 0; mt < 2; ++mt)
#pragma unroll
            for (int nt = 0; nt < 8; ++nt)
                p[mt][nt] = __builtin_amdgcn_mfma_f32_16x16x32_bf16(a2[mt], b2[nt], p[mt][nt], 0, 0, 0);
    }

    float pw[8];
#pragma unroll
    for (int nt = 0; nt < 8; ++nt) pw[nt] = 0.f;

#pragma unroll
    for (int mt = 0; mt < 2; ++mt) {
#pragma unroll
        for (int rr = 0; rr < 4; ++rr) {
            const int srow = wv * 32 + mt * 16 + q * 4 + rr;
            float mx = p[mt][0][rr];
#pragma unroll
            for (int nt = 1; nt < 8; ++nt) mx = fmaxf(mx, p[mt][nt][rr]);
#pragma unroll
            for (int off = 1; off < 16; off <<= 1) mx = fmaxf(mx, __shfl_xor(mx, off));
            float e[8];
            float l = 0.f;
#pragma unroll
            for (int nt = 0; nt < 8; ++nt) {
                e[nt] = __expf((p[mt][nt][rr] - mx) * 0.125f);
                l += e[nt];
            }
#pragma unroll
            for (int off = 1; off < 16; off <<= 1) l += __shfl_xor(l, off);
            const float c = Wo[srow] / l;
#pragma unroll
            for (int nt = 0; nt < 8; ++nt) pw[nt] = fmaf(c, e[nt], pw[nt]);
        }
    }
#pragma unroll
    for (int nt = 0; nt < 8; ++nt) {
        pw[nt] += __shfl_xor(pw[nt], 16);
        pw[nt] += __shfl_xor(pw[nt], 32);
    }
    if (q == 0) {
#pragma unroll
        for (int nt = 0; nt < 8; ++nt) sm.wpart[wv][nt * 16 + l15] = pw[nt];
    }
    __syncthreads();
    if (tid < S)
        sm.wfin[tid] = sm.wpart[0][tid] + sm.wpart[1][tid] + sm.wpart[2][tid] + sm.wpart[3][tid];
    __syncthreads();

    {
        const int dd   = tid >> 2;
        const int part = tid & 3;
        const float* xv = xb + (size_t)(h * D + dd) * S + part * 32;
        float a5 = 0.f;
#pragma unroll 8
        for (int t = 0; t < 32; ++t) a5 = fmaf(sm.wfin[part * 32 + t], xv[t], a5);
        a5 += __shfl_xor(a5, 1);
        a5 += __shfl_xor(a5, 2);
        if (part == 0) out[(size_t)b * F + h * D + dd] = a5 + bo[0];
    }
}

extern "C" void kernel_launch(void* const* d_in, const int* in_sizes, int n_in,
                              void* d_out, int out_size, void* d_ws, size_t ws_size,
                              hipStream_t stream) {
    const float* x  = (const float*)d_in[0];
    const float* Wq = (const float*)d_in[1];
    const float* bq = (const float*)d_in[2];
    const float* Wk = (const float*)d_in[3];
    const float* bk = (const float*)d_in[4];
    const float* Wo = (const float*)d_in[5];
    const float* bo = (const float*)d_in[6];
    float* out = (float*)d_out;

    if (ws_size >= WS_NEED) {
        uint4* xsp = (uint4*)d_ws;
        uint4* wbp = (uint4*)((char*)d_ws + XS_UNITS * 16);
        static bool attr_done = false;
        if (!attr_done) {
            (void)hipFuncSetAttribute(reinterpret_cast<const void*>(attn_main),
                                      hipFuncAttributeMaxDynamicSharedMemorySize, MAIN_LDS_BYTES);
            attr_done = true;
        }
        prep<<<dim3(4096 + 256), dim3(256), 0, stream>>>(x, Wq, Wk, xsp, wbp);
        attn_main<<<dim3(1024), dim3(512), MAIN_LDS_BYTES, stream>>>(x, xsp, wbp, bq, bk, Wo, bo, out);
    } else {
        attn_fallback<<<dim3(256 * H), dim3(256), 0, stream>>>(x, Wq, bq, Wk, bk, Wo, bo, out);
    }
}

// Round 5
// 342.086 us; speedup vs baseline: 1.1617x; 1.0319x over previous
//
#include <hip/hip_runtime.h>

#define F 1024
#define S 128
#define H 16
#define D 64
#define CK 64        // K per tile (BK)
#define NCHUNK 16    // 1024 / 64

typedef short bf16x8 __attribute__((ext_vector_type(8)));
typedef float f32x4  __attribute__((ext_vector_type(4)));

// ws: xs2[128 bg][16 ch][2048 units] (B-tiles: rows = 2 batches' s, k-major)
//     wb2[ 8 hg][16 ch][2048 units] (A-tiles: rows = 2 heads' [Wq;Wk], k-major)
// unit(kc,row) = kc*256 + row ; kc in [0,8) (8 bf16 of k each), row in [0,256)
#define XS_UNITS ((size_t)128 * NCHUNK * 2048)
#define WB_UNITS ((size_t)8 * NCHUNK * 2048)
#define WS_NEED ((XS_UNITS + WB_UNITS) * 16)

#define MAIN_LDS_BYTES (8192 * 16 + 8 * 128 * 4 + 128 * 4)

__device__ __forceinline__ unsigned short f2bf(float f) {
    unsigned u = __float_as_uint(f);
    u += 0x7fffu + ((u >> 16) & 1u);   // round-to-nearest-even
    return (unsigned short)(u >> 16);
}

__device__ __forceinline__ uint4 pack8(const float* f) {
    uint4 u;
    u.x = (unsigned)f2bf(f[0]) | ((unsigned)f2bf(f[1]) << 16);
    u.y = (unsigned)f2bf(f[2]) | ((unsigned)f2bf(f[3]) << 16);
    u.z = (unsigned)f2bf(f[4]) | ((unsigned)f2bf(f[5]) << 16);
    u.w = (unsigned)f2bf(f[6]) | ((unsigned)f2bf(f[7]) << 16);
    return u;
}

typedef __attribute__((address_space(1))) const unsigned int as1_u32;
typedef __attribute__((address_space(3))) unsigned int as3_u32;

__device__ __forceinline__ void async_cp16(const uint4* g, uint4* l) {
    __builtin_amdgcn_global_load_lds((as1_u32*)g, (as3_u32*)l, 16, 0, 0);
}

__device__ __forceinline__ void bar()   { __builtin_amdgcn_s_barrier(); }
__device__ __forceinline__ void sb0()   { __builtin_amdgcn_sched_barrier(0); }

template<int N> __device__ __forceinline__ void lgkm() {
    asm volatile("s_waitcnt lgkmcnt(%0)" :: "n"(N));
}
template<int N> __device__ __forceinline__ void vmw() {
    asm volatile("s_waitcnt vmcnt(%0)" :: "n"(N));
}

// ---------------- prep: fp32 -> bf16, k-major tiles; direct coalesced transpose (no LDS) ----------------
__global__ void prep(const float* __restrict__ x,
                     const float* __restrict__ Wq,
                     const float* __restrict__ Wk,
                     uint4* __restrict__ xs,
                     uint4* __restrict__ wb)
{
    const int tid = threadIdx.x;
    const int blk = blockIdx.x;
    if (blk < 4096) {
        // x tile: (b, ch). unit (kc, s) <- x[b][ch*64 + kc*8 + jj][s], jj=0..7.
        // For fixed (j, jj), lanes read consecutive s -> fully coalesced rows.
        const int b = blk >> 4, ch = blk & 15;
        const float* xb = x + ((size_t)b * F + ch * CK) * S;
        uint4* dst = xs + ((size_t)(b >> 1) * NCHUNK + ch) * 2048 + (b & 1) * 128;
#pragma unroll
        for (int j = 0; j < 4; ++j) {
            const int u  = tid + j * 256;
            const int kc = u >> 7;
            const int s  = u & 127;
            const float* rp = xb + (size_t)(kc * 8) * S + s;
            float f[8];
#pragma unroll
            for (int jj = 0; jj < 8; ++jj) f[jj] = rp[jj * S];
            dst[kc * 256 + s] = pack8(f);
        }
    } else {
        // W tile: (h, ch) -> unit = kc*256 + (h&1)*128 + m ; m<64 -> Wq row, else Wk row
        const int blk2 = blk - 4096;
        const int h = blk2 >> 4, ch = blk2 & 15;
        uint4* dst = wb + ((size_t)(h >> 1) * NCHUNK + ch) * 2048 + (h & 1) * 128;
#pragma unroll
        for (int j = 0; j < 4; ++j) {
            const int u  = tid + j * 256;
            const int kc = u >> 7;
            const int m  = u & 127;
            const float* srcp = (m < 64)
                ? (Wq + (size_t)(h * D + m) * F + ch * CK + kc * 8)
                : (Wk + (size_t)(h * D + m - 64) * F + ch * CK + kc * 8);
            float f[8];
            float4 a = ((const float4*)srcp)[0];
            float4 c = ((const float4*)srcp)[1];
            f[0] = a.x; f[1] = a.y; f[2] = a.z; f[3] = a.w;
            f[4] = c.x; f[5] = c.y; f[6] = c.z; f[7] = c.w;
            dst[kc * 256 + m] = pack8(f);
        }
    }
}

// ---------------- main kernel helpers ----------------
__device__ __forceinline__ void read4(const uint4* mat, int base, bf16x8 (&r)[4]) {
    r[0] = *(const bf16x8*)&mat[base];
    r[1] = *(const bf16x8*)&mat[base + 16];
    r[2] = *(const bf16x8*)&mat[base + 32];
    r[3] = *(const bf16x8*)&mat[base + 48];
}

template<int RB>
__device__ __forceinline__ void mfma16(f32x4 (&acc)[8][4], const bf16x8 (&af)[4], const bf16x8 (&br)[4]) {
#pragma unroll
    for (int mt = 0; mt < 4; ++mt)
#pragma unroll
        for (int nt = 0; nt < 4; ++nt)
            acc[RB + mt][nt] = __builtin_amdgcn_mfma_f32_16x16x32_bf16(af[mt], br[nt], acc[RB + mt][nt], 0, 0, 0);
}

// half-tiles (16 KB each): 0 = A.ks0, 1 = B.ks0, 2 = A.ks1, 3 = B.ks1
template<int HALF>
__device__ __forceinline__ void stage_half(uint4* mat, const uint4* wbase, const uint4* xbase,
                                           int tgt, int wv, int lane) {
    const int bufb = (tgt & 1) * 4096;
    const uint4* g;
    int l;
    if constexpr (HALF == 0)      { g = wbase + (size_t)tgt * 2048;        l = bufb;        }
    else if constexpr (HALF == 1) { g = xbase + (size_t)tgt * 2048;        l = bufb + 2048; }
    else if constexpr (HALF == 2) { g = wbase + (size_t)tgt * 2048 + 1024; l = bufb + 1024; }
    else                          { g = xbase + (size_t)tgt * 2048 + 1024; l = bufb + 3072; }
    async_cp16(g + wv * 128 + lane,      &mat[l + wv * 128]);
    async_cp16(g + wv * 128 + 64 + lane, &mat[l + wv * 128 + 64]);
}

// One K-tile (BK=64), low-sync AITER-style schedule: 2 barriers/tile, counted lgkm/vmcnt.
// Hazard ledger:
//  - RAW (DMA->ds_read): ks1 regions (h2,h3(t)) published at mid-tile {vmw<4>; bar}.
//    vmw<4> leaves only h2,h3(t+1) outstanding -> h2,h3(t) (and h0,h1(t+1)) drained per-wave;
//    barrier publishes across waves.
//  - next tile's ks0 (h0,h1(t+1)): drained at mid-tile vmw<4>, published by same barrier.
//  - WAR (stage h0,h1(t+2) overwrites CUR ks0 regions): every wave did lgkm<0> (all ks0 reads
//    complete) before the mid-tile barrier; stages of h0,h1(t+2) issue after it.
//  - WAR (stage h2(t+2) in tile t+1 overwrites CUR^? ks1 regions read in tile t): tile-t ks1
//    reads complete before tile-t end barrier (lgkm<0> before MFMA3); stage issues after it.
template<int CUR, int SMODE>   // SMODE: 2=stage t+1 & t+2 halves, 1=only h2,h3(t+1), 0=none
__device__ __forceinline__ void ktile2(uint4* mat, const uint4* wbase, const uint4* xbase,
                                       int t, int wv, int lane, int wm, int wn, int q, int l15,
                                       f32x4 (&acc)[8][4])
{
    const int ab = CUR * 4096 + wm * 128 + l15 + q * 256;
    const int bb = CUR * 4096 + 2048 + wn * 64 + l15 + q * 256;
    {
        bf16x8 a0[4], a1[4], b0[4];
        read4(mat, ab, a0);
        read4(mat, bb, b0);
        read4(mat, ab + 64, a1);
        sb0();
        if constexpr (SMODE >= 1) stage_half<2>(mat, wbase, xbase, t + 1, wv, lane);
        sb0();
        lgkm<4>(); sb0();
        __builtin_amdgcn_s_setprio(1); mfma16<0>(acc, a0, b0); __builtin_amdgcn_s_setprio(0); sb0();
        if constexpr (SMODE >= 1) stage_half<3>(mat, wbase, xbase, t + 1, wv, lane);
        sb0();
        lgkm<0>(); sb0();
        __builtin_amdgcn_s_setprio(1); mfma16<4>(acc, a1, b0); __builtin_amdgcn_s_setprio(0); sb0();
    }
    if constexpr (SMODE >= 1) { vmw<4>(); } else { vmw<0>(); }
    bar(); sb0();
    {
        bf16x8 a2[4], a3[4], b1[4];
        read4(mat, ab + 1024, a2);
        read4(mat, bb + 1024, b1);
        read4(mat, ab + 1024 + 64, a3);
        sb0();
        if constexpr (SMODE == 2) stage_half<0>(mat, wbase, xbase, t + 2, wv, lane);
        sb0();
        lgkm<4>(); sb0();
        __builtin_amdgcn_s_setprio(1); mfma16<0>(acc, a2, b1); __builtin_amdgcn_s_setprio(0); sb0();
        if constexpr (SMODE == 2) stage_half<1>(mat, wbase, xbase, t + 2, wv, lane);
        sb0();
        lgkm<0>(); sb0();
        __builtin_amdgcn_s_setprio(1); mfma16<4>(acc, a3, b1); __builtin_amdgcn_s_setprio(0); sb0();
    }
    bar(); sb0();
}

// ---------------- main: 256x256x1024 GEMM (2 heads x 2 batches) + pair-parallel attention epilogue ----------------
__launch_bounds__(512, 2)
__global__ void attn_main(const float* __restrict__ x,
                          const uint4* __restrict__ xs,
                          const uint4* __restrict__ wb,
                          const float* __restrict__ bq,
                          const float* __restrict__ bk,
                          const float* __restrict__ Wo,
                          const float* __restrict__ bo,
                          float* __restrict__ out)
{
    (void)x;
    extern __shared__ char smraw[];
    uint4* mat   = (uint4*)smraw;                       // 8192 units = 2 x (A 2048 + B 2048)
    float* wpart = (float*)(smraw + 8192 * 16);         // [8][128]

    const int tid  = threadIdx.x;
    const int lane = tid & 63;
    const int wv   = tid >> 6;
    const int l15  = lane & 15;
    const int q    = lane >> 4;
    const int wm   = wv >> 2;      // 2 waves rows
    const int wn   = wv & 3;       // 4 waves cols

    // XCD-aware swizzle: 1024 blocks, 8 XCDs; per XCD 16 bg x 8 hg
    const int g    = blockIdx.x;
    const int xcd  = g & 7;
    const int slot = g >> 3;
    const int bg   = xcd * 16 + (slot & 15);   // batch-pair [0,128)
    const int hg   = slot >> 4;                // head-pair  [0,8)

    const uint4* wbase = wb + (size_t)hg * NCHUNK * 2048;
    const uint4* xbase = xs + (size_t)bg * NCHUNK * 2048;

    f32x4 acc[8][4];
#pragma unroll
    for (int mi = 0; mi < 8; ++mi)
#pragma unroll
        for (int ni = 0; ni < 4; ++ni) acc[mi][ni] = (f32x4){0.f, 0.f, 0.f, 0.f};

    // prologue: tile0 all 4 halves + tile1 ks0 halves (12 loads/wave);
    // vmw<4> drains h0..h3(0) (keeps h0,h1(1) in flight), barrier publishes.
    stage_half<0>(mat, wbase, xbase, 0, wv, lane);
    stage_half<1>(mat, wbase, xbase, 0, wv, lane);
    stage_half<2>(mat, wbase, xbase, 0, wv, lane);
    stage_half<3>(mat, wbase, xbase, 0, wv, lane);
    stage_half<0>(mat, wbase, xbase, 1, wv, lane);
    stage_half<1>(mat, wbase, xbase, 1, wv, lane);
    vmw<4>();
    bar(); sb0();

#pragma unroll 1
    for (int i = 0; i < 7; ++i) {
        ktile2<0, 2>(mat, wbase, xbase, 2 * i,     wv, lane, wm, wn, q, l15, acc);
        ktile2<1, 2>(mat, wbase, xbase, 2 * i + 1, wv, lane, wm, wn, q, l15, acc);
    }
    ktile2<0, 1>(mat, wbase, xbase, 14, wv, lane, wm, wn, q, l15, acc);
    ktile2<1, 0>(mat, wbase, xbase, 15, wv, lane, wm, wn, q, l15, acc);

    __syncthreads();

    // C-write: +bias, bf16, write 4 combos' Qs/Ks into LDS (combo c, 2048 units each)
    {
        unsigned short* m16 = (unsigned short*)mat;
        const int hglobw = hg * 2 + wm;
#pragma unroll
        for (int rt = 0; rt < 8; ++rt) {
            const int mh0   = rt * 16 + q * 4;          // rows mh0..mh0+3 (within head's [Wq;Wk])
            const int d0    = mh0 & 63;
            const int kbase = (mh0 < 64) ? 0 : 1024;
            float bias4[4];
#pragma unroll
            for (int rr = 0; rr < 4; ++rr)
                bias4[rr] = (mh0 < 64) ? bq[hglobw * D + d0 + rr] : bk[hglobw * D + d0 + rr];
#pragma unroll
            for (int ct = 0; ct < 4; ++ct) {
                const int col = wn * 64 + ct * 16 + l15;
                const int bj  = col >> 7;
                const int s   = col & 127;
                const int c   = wm * 2 + bj;
                unsigned long long pv = 0;
#pragma unroll
                for (int rr = 0; rr < 4; ++rr)
                    pv |= (unsigned long long)f2bf(acc[rt][ct][rr] + bias4[rr]) << (16 * rr);
                const int unit = c * 2048 + kbase + s * 8 + ((d0 >> 3) ^ (s & 7));
                *(unsigned long long*)&m16[unit * 8 + (d0 & 7)] = pv;   // 8B-aligned (d0&7 in {0,4})
            }
        }
    }
    __syncthreads();

    // ---- pair-parallel epilogue: waves {2c,2c+1} own combo c; all combos concurrent ----
    const int ce   = ((wv >> 2) << 1) | ((wv >> 1) & 1);   // this wave's combo
    const int half = wv & 1;                               // s-row half within combo
    const int qb = ce * 2048;
    const int kb = ce * 2048 + 1024;
    const int bglob = bg * 2 + (ce & 1);
    const int hglob = hg * 2 + (ce >> 1);

    // phase 2: scores for s-rows [half*64, +64), all 128 t
    f32x4 p[4][8];
#pragma unroll
    for (int mt = 0; mt < 4; ++mt)
#pragma unroll
        for (int nt = 0; nt < 8; ++nt) p[mt][nt] = (f32x4){0.f, 0.f, 0.f, 0.f};
#pragma unroll
    for (int ks = 0; ks < 2; ++ks) {
        const int kcq = ks * 4 + q;
        bf16x8 a2[4], b2[8];
#pragma unroll
        for (int mt = 0; mt < 4; ++mt) {
            const int row = half * 64 + mt * 16 + l15;
            a2[mt] = *(const bf16x8*)&mat[qb + row * 8 + (kcq ^ (row & 7))];
        }
#pragma unroll
        for (int nt = 0; nt < 8; ++nt) {
            const int trow = nt * 16 + l15;
            b2[nt] = *(const bf16x8*)&mat[kb + trow * 8 + (kcq ^ (trow & 7))];
        }
#pragma unroll
        for (int mt = 0; mt < 4; ++mt)
#pragma unroll
            for (int nt = 0; nt < 8; ++nt)
                p[mt][nt] = __builtin_amdgcn_mfma_f32_16x16x32_bf16(a2[mt], b2[nt], p[mt][nt], 0, 0, 0);
    }

    // phase-5 loads issued EARLY (hidden under softmax): coalesced uint4 from xs, chunk ch = hglob
    const int ell = half * 64 + lane;
    const int kc5 = ell >> 4;
    const int sg5 = ell & 15;
    const uint4* xsrc = xbase + (size_t)hglob * 2048 + kc5 * 256 + (ce & 1) * 128 + sg5 * 8;
    uint4 xu[8];
#pragma unroll
    for (int jj = 0; jj < 8; ++jj) xu[jj] = xsrc[jj];

    // phases 3+4: softmax (no max-sub; scores ~N(0,1), clamp insurance) + fold Wo
    float pw[8];
#pragma unroll
    for (int nt = 0; nt < 8; ++nt) pw[nt] = 0.f;
#pragma unroll
    for (int mt = 0; mt < 4; ++mt) {
#pragma unroll
        for (int rr = 0; rr < 4; ++rr) {
            const int srow = half * 64 + mt * 16 + q * 4 + rr;
            float e[8];
            float l = 0.f;
#pragma unroll
            for (int nt = 0; nt < 8; ++nt) {
                e[nt] = __expf(fminf(p[mt][nt][rr] * 0.125f, 80.f));   // 1/TEMP = 1/8
                l += e[nt];
            }
#pragma unroll
            for (int off = 1; off < 16; off <<= 1) l += __shfl_xor(l, off);
            const float cw = Wo[srow] / l;
#pragma unroll
            for (int nt = 0; nt < 8; ++nt) pw[nt] = fmaf(cw, e[nt], pw[nt]);
        }
    }
#pragma unroll
    for (int nt = 0; nt < 8; ++nt) {
        pw[nt] += __shfl_xor(pw[nt], 16);
        pw[nt] += __shfl_xor(pw[nt], 32);
    }
    if (q == 0) {
#pragma unroll
        for (int nt = 0; nt < 8; ++nt) wpart[wv * 128 + nt * 16 + l15] = pw[nt];
    }
    __syncthreads();

    // phase 5: out[bglob, hglob*64 + kc5*8 + e] = sum_s w[s] * x_bf16 + bo  (x from regs)
    {
        const float* w0 = wpart + 2 * ce * 128;
        const float* w1 = w0 + 128;
        float acc8[8];
#pragma unroll
        for (int e = 0; e < 8; ++e) acc8[e] = 0.f;
#pragma unroll
        for (int jj = 0; jj < 8; ++jj) {
            const int s = sg5 * 8 + jj;
            const float w = w0[s] + w1[s];
            const unsigned* du = (const unsigned*)&xu[jj];
#pragma unroll
            for (int dw = 0; dw < 4; ++dw) {
                const unsigned v = du[dw];
                acc8[dw * 2 + 0] = fmaf(__uint_as_float(v << 16), w, acc8[dw * 2 + 0]);
                acc8[dw * 2 + 1] = fmaf(__uint_as_float(v & 0xffff0000u), w, acc8[dw * 2 + 1]);
            }
        }
#pragma unroll
        for (int e = 0; e < 8; ++e) {
#pragma unroll
            for (int off = 1; off < 16; off <<= 1)
                acc8[e] += __shfl_xor(acc8[e], off);
        }
        if (sg5 < 8)
            out[(size_t)bglob * F + hglob * D + kc5 * 8 + sg5] = acc8[sg5] + bo[0];
    }
}

// ---------------- fallback (self-contained) if ws too small ----------------
struct SmemT {
    uint4 mat[2048];
    float wpart[4][S];
    float wfin[S];
};

__launch_bounds__(256, 4)
__global__ void attn_fallback(const float* __restrict__ x,
                              const float* __restrict__ Wq,
                              const float* __restrict__ bq,
                              const float* __restrict__ Wk,
                              const float* __restrict__ bk,
                              const float* __restrict__ Wo,
                              const float* __restrict__ bo,
                              float* __restrict__ out)
{
    __shared__ SmemT sm;
    const int tid  = threadIdx.x;
    const int lane = tid & 63;
    const int wv   = tid >> 6;
    const int l15  = lane & 15;
    const int q    = lane >> 4;

    const int g    = blockIdx.x;
    const int xcd  = g & 7;
    const int slot = g >> 3;
    const int hg   = slot >> 7;
    const int r0   = slot & 127;
    const int b    = xcd * 32 + (r0 >> 2);
    const int h    = hg * 4 + (r0 & 3);

    const float* xb  = x  + (size_t)b * (F * S);
    const float* wqh = Wq + (size_t)h * D * F;
    const float* wkh = Wk + (size_t)h * D * F;

    const int m0 = (wv & 1) * 64;
    const int n0 = (wv >> 1) * 64;

    f32x4 acc[4][4];
#pragma unroll
    for (int mt = 0; mt < 4; ++mt)
#pragma unroll
        for (int nt = 0; nt < 4; ++nt) acc[mt][nt] = (f32x4){0.f, 0.f, 0.f, 0.f};

    const int mq  = tid >> 2;
    const int kq  = tid & 3;
    const int s0x = (tid & 63) * 2;
    const int iq  = tid >> 6;

    for (int ch = 0; ch < NCHUNK; ++ch) {
        const int c0 = ch * CK;
        __syncthreads();
        {
            const int key = mq & 7;
            float f[16];
            const float4* srcq = (const float4*)(wqh + (size_t)mq * F + (c0 + kq * 16));
#pragma unroll
            for (int j = 0; j < 4; ++j) {
                float4 v = srcq[j];
                f[4*j] = v.x; f[4*j+1] = v.y; f[4*j+2] = v.z; f[4*j+3] = v.w;
            }
            sm.mat[mq * 8 + ((kq * 2    ) ^ key)] = pack8(f);
            sm.mat[mq * 8 + ((kq * 2 + 1) ^ key)] = pack8(f + 8);
            const float4* srck = (const float4*)(wkh + (size_t)mq * F + (c0 + kq * 16));
#pragma unroll
            for (int j = 0; j < 4; ++j) {
                float4 v = srck[j];
                f[4*j] = v.x; f[4*j+1] = v.y; f[4*j+2] = v.z; f[4*j+3] = v.w;
            }
            sm.mat[(64 + mq) * 8 + ((kq * 2    ) ^ key)] = pack8(f);
            sm.mat[(64 + mq) * 8 + ((kq * 2 + 1) ^ key)] = pack8(f + 8);
        }
        {
            const float* src = xb + (size_t)(c0 + iq * 16) * S + s0x;
            float fa[8], fb[8];
#pragma unroll
            for (int grp = 0; grp < 2; ++grp) {
#pragma unroll
                for (int j = 0; j < 8; ++j) {
                    float2 v = *(const float2*)(src + (size_t)(grp * 8 + j) * S);
                    fa[j] = v.x; fb[j] = v.y;
                }
                const int kc = iq * 2 + grp;
                sm.mat[1024 + (s0x    ) * 8 + (kc ^ ((s0x    ) & 7))] = pack8(fa);
                sm.mat[1024 + (s0x + 1) * 8 + (kc ^ ((s0x + 1) & 7))] = pack8(fb);
            }
        }
        __syncthreads();
#pragma unroll
        for (int ks = 0; ks < 2; ++ks) {
            bf16x8 af[4], br[4];
#pragma unroll
            for (int mt = 0; mt < 4; ++mt) {
                const int row = m0 + mt * 16 + l15;
                af[mt] = *(const bf16x8*)&sm.mat[row * 8 + ((ks * 4 + q) ^ (row & 7))];
            }
#pragma unroll
            for (int nt = 0; nt < 4; ++nt) {
                const int row = n0 + nt * 16 + l15;
                br[nt] = *(const bf16x8*)&sm.mat[1024 + row * 8 + ((ks * 4 + q) ^ (row & 7))];
            }
#pragma unroll
            for (int mt = 0; mt < 4; ++mt)
#pragma unroll
                for (int nt = 0; nt < 4; ++nt)
                    acc[mt][nt] = __builtin_amdgcn_mfma_f32_16x16x32_bf16(
                        af[mt], br[nt], acc[mt][nt], 0, 0, 0);
        }
    }

    __syncthreads();
    {
        unsigned short* m16 = (unsigned short*)sm.mat;
#pragma unroll
        for (int mt = 0; mt < 4; ++mt) {
#pragma unroll
            for (int rr = 0; rr < 4; ++rr) {
                const int m = m0 + mt * 16 + q * 4 + rr;
                const int d = m & 63;
                const float bias = (m < 64) ? bq[h * D + d] : bk[h * D + d];
                const int base = (m < 64) ? 0 : 8192;
#pragma unroll
                for (int nt = 0; nt < 4; ++nt) {
                    const int s = n0 + nt * 16 + l15;
                    const float v = acc[mt][nt][rr] + bias;
                    const int unit = s * 8 + (((d >> 3)) ^ (s & 7));
                    m16[base + unit * 8 + (d & 7)] = f2bf(v);
                }
            }
        }
    }
    __syncthreads();

    f32x4 p[2][8];
#pragma unroll
    for (int mt = 0; mt < 2; ++mt)
#pragma unroll
        for (int nt = 0; nt < 8; ++nt) p[mt][nt] = (f32x4){0.f, 0.f, 0.f, 0.f};

#pragma unroll
    for (int ks = 0; ks < 2; ++ks) {
        bf16x8 a2[2], b2[8];
#pragma unroll
        for (int mt = 0; mt < 2; ++mt) {
            const int row = wv * 32 + mt * 16 + l15;
            a2[mt] = *(const bf16x8*)&sm.mat[row * 8 + ((ks * 4 + q) ^ (row & 7))];
        }
#pragma unroll
        for (int nt = 0; nt < 8; ++nt) {
            const int row = nt * 16 + l15;
            b2[nt] = *(const bf16x8*)&sm.mat[1024 + row * 8 + ((ks * 4 + q) ^ (row & 7))];
        }
#pragma unroll
        for (int mt = 0; mt < 2; ++mt)
#pragma unroll
            for (int nt = 0; nt < 8; ++nt)
                p[mt][nt] = __builtin_amdgcn_mfma_f32_16x16x32_bf16(a2[mt], b2[nt], p[mt][nt], 0, 0, 0);
    }

    float pw[8];
#pragma unroll
    for (int nt = 0; nt < 8; ++nt) pw[nt] = 0.f;

#pragma unroll
    for (int mt = 0; mt < 2; ++mt) {
#pragma unroll
        for (int rr = 0; rr < 4; ++rr) {
            const int srow = wv * 32 + mt * 16 + q * 4 + rr;
            float mx = p[mt][0][rr];
#pragma unroll
            for (int nt = 1; nt < 8; ++nt) mx = fmaxf(mx, p[mt][nt][rr]);
#pragma unroll
            for (int off = 1; off < 16; off <<= 1) mx = fmaxf(mx, __shfl_xor(mx, off));
            float e[8];
            float l = 0.f;
#pragma unroll
            for (int nt = 0; nt < 8; ++nt) {
                e[nt] = __expf((p[mt][nt][rr] - mx) * 0.125f);
                l += e[nt];
            }
#pragma unroll
            for (int off = 1; off < 16; off <<= 1) l += __shfl_xor(l, off);
            const float c = Wo[srow] / l;
#pragma unroll
            for (int nt = 0; nt < 8; ++nt) pw[nt] = fmaf(c, e[nt], pw[nt]);
        }
    }
#pragma unroll
    for (int nt = 0; nt < 8; ++nt) {
        pw[nt] += __shfl_xor(pw[nt], 16);
        pw[nt] += __shfl_xor(pw[nt], 32);
    }
    if (q == 0) {
#pragma unroll
        for (int nt = 0; nt < 8; ++nt) sm.wpart[wv][nt * 16 + l15] = pw[nt];
    }
    __syncthreads();
    if (tid < S)
        sm.wfin[tid] = sm.wpart[0][tid] + sm.wpart[1][tid] + sm.wpart[2][tid] + sm.wpart[3][tid];
    __syncthreads();

    {
        const int dd   = tid >> 2;
        const int part = tid & 3;
        const float* xv = xb + (size_t)(h * D + dd) * S + part * 32;
        float a5 = 0.f;
#pragma unroll 8
        for (int t = 0; t < 32; ++t) a5 = fmaf(sm.wfin[part * 32 + t], xv[t], a5);
        a5 += __shfl_xor(a5, 1);
        a5 += __shfl_xor(a5, 2);
        if (part == 0) out[(size_t)b * F + h * D + dd] = a5 + bo[0];
    }
}

extern "C" void kernel_launch(void* const* d_in, const int* in_sizes, int n_in,
                              void* d_out, int out_size, void* d_ws, size_t ws_size,
                              hipStream_t stream) {
    const float* x  = (const float*)d_in[0];
    const float* Wq = (const float*)d_in[1];
    const float* bq = (const float*)d_in[2];
    const float* Wk = (const float*)d_in[3];
    const float* bk = (const float*)d_in[4];
    const float* Wo = (const float*)d_in[5];
    const float* bo = (const float*)d_in[6];
    float* out = (float*)d_out;

    if (ws_size >= WS_NEED) {
        uint4* xsp = (uint4*)d_ws;
        uint4* wbp = (uint4*)((char*)d_ws + XS_UNITS * 16);
        static bool attr_done = false;
        if (!attr_done) {
            (void)hipFuncSetAttribute(reinterpret_cast<const void*>(attn_main),
                                      hipFuncAttributeMaxDynamicSharedMemorySize, MAIN_LDS_BYTES);
            attr_done = true;
        }
        prep<<<dim3(4096 + 256), dim3(256), 0, stream>>>(x, Wq, Wk, xsp, wbp);
        attn_main<<<dim3(1024), dim3(512), MAIN_LDS_BYTES, stream>>>(x, xsp, wbp, bq, bk, Wo, bo, out);
    } else {
        attn_fallback<<<dim3(256 * H), dim3(256), 0, stream>>>(x, Wq, bq, Wk, bk, Wo, bo, out);
    }
}